// Round 6
// baseline (86.650 us; speedup 1.0000x reference)
//
#include <hip/hip_runtime.h>

// Problem constants: B=2,S=512,E=1024; G=4,H=8,Q=16,D=2,V=16,N=512
// bgh = (b*4+g)*8+h in [0,64); sd in [0,1024); n in [0,512)

typedef __attribute__((ext_vector_type(4))) short bf16x4;
typedef __attribute__((ext_vector_type(8))) short short8;
typedef __attribute__((ext_vector_type(8))) unsigned short ushort8;
typedef __attribute__((ext_vector_type(8))) __bf16 bf16x8_t;
typedef __attribute__((ext_vector_type(4))) float f32x4;

static __device__ __forceinline__ unsigned short f2bf(float f) {
  union { float f; unsigned u; } v; v.f = f;
  unsigned r = v.u + 0x7fffu + ((v.u >> 16) & 1u);
  return (unsigned short)(r >> 16);
}

#if defined(__has_builtin)
#if __has_builtin(__builtin_amdgcn_mfma_f32_16x16x16bf16_1k)
#define HAVE_MFMA16 1
#endif
#if __has_builtin(__builtin_amdgcn_mfma_f32_16x16x32_bf16)
#define HAVE_MFMA32 1
#endif
#endif

static __device__ __forceinline__ f32x4 mfma16(bf16x4 a, bf16x4 b, f32x4 c) {
#ifdef HAVE_MFMA16
  return __builtin_amdgcn_mfma_f32_16x16x16bf16_1k(a, b, c, 0, 0, 0);
#else
  f32x4 d;
  asm volatile("v_mfma_f32_16x16x16_bf16 %0, %1, %2, %3\n\t"
               "s_nop 7\n\ts_nop 7"
               : "=&v"(d)
               : "v"(a), "v"(b), "v"(c));
  return d;
#endif
}

#ifdef HAVE_MFMA32
static __device__ __forceinline__ f32x4 mfma32(short8 a, short8 b, f32x4 c) {
  return __builtin_amdgcn_mfma_f32_16x16x32_bf16(
      __builtin_bit_cast(bf16x8_t, a), __builtin_bit_cast(bf16x8_t, b), c, 0, 0, 0);
}
#endif

// ---------------------------------------------------------------------------
// Prep (single launch, 1088 blocks):
//   [0,256)    : Wq  f32 -> WqT[n][k] bf16 (64x64 tile transpose)
//   [256,512)  : Wre f32 -> WreT[n][k] bf16
//   [512,576)  : keys/values -> KTb[bgh][n][16q], VTb[bgh][16v][512n] bf16
//   [576,1088) : emb f32 -> bf16 (straight convert)
// ---------------------------------------------------------------------------
__global__ __launch_bounds__(256) void prep_all(
    const float* __restrict__ Wq, const float* __restrict__ Wre,
    const float* __restrict__ keys, const float* __restrict__ values,
    const float* __restrict__ emb,
    unsigned short* __restrict__ WqT, unsigned short* __restrict__ WreT,
    unsigned short* __restrict__ KTb, unsigned short* __restrict__ VTb,
    unsigned short* __restrict__ embb) {
  __shared__ __align__(16) unsigned short t[64][72];
  const int blk = blockIdx.x;
  const int tid = threadIdx.x;

  if (blk < 512) {
    const float* W = (blk < 256) ? Wq : Wre;
    unsigned short* WT = (blk < 256) ? WqT : WreT;
    const int idx = blk & 255;
    const int bx = (idx & 15) * 64, by = (idx >> 4) * 64;
    const int r = tid >> 2;
    const int c0 = (tid & 3) * 16;
#pragma unroll
    for (int j = 0; j < 16; j += 4) {
      float4 v = *reinterpret_cast<const float4*>(&W[(long)(by + r) * 1024 + bx + c0 + j]);
      t[c0 + j + 0][r] = f2bf(v.x);
      t[c0 + j + 1][r] = f2bf(v.y);
      t[c0 + j + 2][r] = f2bf(v.z);
      t[c0 + j + 3][r] = f2bf(v.w);
    }
    __syncthreads();
#pragma unroll
    for (int j = 0; j < 16; j += 8) {
      *reinterpret_cast<ushort8*>(&WT[(long)(bx + r) * 1024 + by + c0 + j]) =
          *reinterpret_cast<const ushort8*>(&t[r][c0 + j]);
    }
  } else if (blk < 576) {
    const int kvIdx = blk - 512;
    const int bg = kvIdx >> 3, nb = kvIdx & 7;
    const long src_base = (long)bg * 512 * 128 + (long)nb * 64 * 128;
#pragma unroll
    for (int i = 0; i < 8; ++i) {
      int idx = tid + i * 256;
      int nl = idx >> 5, c4 = idx & 31;
      int n = nb * 64 + nl;
      float4 kv = *reinterpret_cast<const float4*>(&keys[src_base + nl * 128 + c4 * 4]);
      float4 vv = *reinterpret_cast<const float4*>(&values[src_base + nl * 128 + c4 * 4]);
      float kk[4] = {kv.x, kv.y, kv.z, kv.w};
      float vl[4] = {vv.x, vv.y, vv.z, vv.w};
#pragma unroll
      for (int cc = 0; cc < 4; ++cc) {
        int col = c4 * 4 + cc;          // qq*8 + h
        int h = col & 7, qv = col >> 3;
        int bgh = bg * 8 + h;
        KTb[((long)bgh * 512 + n) * 16 + qv] = f2bf(kk[cc]);
        VTb[((long)bgh * 16 + qv) * 512 + n] = f2bf(vl[cc]);
      }
    }
  } else {
    const long i = ((long)(blk - 576) * 256 + tid) * 8;
    float4 a = *reinterpret_cast<const float4*>(&emb[i]);
    float4 b = *reinterpret_cast<const float4*>(&emb[i + 4]);
    ushort8 o;
    o[0] = f2bf(a.x); o[1] = f2bf(a.y); o[2] = f2bf(a.z); o[3] = f2bf(a.w);
    o[4] = f2bf(b.x); o[5] = f2bf(b.y); o[6] = f2bf(b.z); o[7] = f2bf(b.w);
    *reinterpret_cast<ushort8*>(&embb[i]) = o;
  }
}

// ---------------------------------------------------------------------------
// Split-K bf16 MFMA GEMM: P[split] += A[m][kslice] @ BT[n][kslice]^T.
// grid (256 tiles, 4 splits); tile 64x64, 256 thr = 4 waves (2x2, wave 32x32);
// K=256 per split, BK=32 (= one mfma32 K-depth): 8 iterations per block.
// This cuts the serial barrier-synced K chain 4x vs K=1024 (the round-5
// latency bottleneck) while keeping 4 blocks/CU occupancy.
// MODE 1: scatter partial f32 to qp[split] in qT layout (+bq in split 0;
//         attn sums the 4 partials — no reduction launch needed).
// MODE 0: row-major partial f32 to wp[split] (reduce_bias sums + bre).
// XCD-chunked tile swizzle (256 tiles, 256%8==0, bijective).
// ---------------------------------------------------------------------------
template <int MODE>
__global__ __launch_bounds__(256) void gemm_splitk(
    const unsigned short* __restrict__ A, const unsigned short* __restrict__ BT,
    const float* __restrict__ bias, float* __restrict__ P) {
  __shared__ __align__(16) unsigned short As[2][64][40];
  __shared__ __align__(16) unsigned short Bs[2][64][40];
  const int tid = threadIdx.x;
  const int bid = blockIdx.x;
  const int split = blockIdx.y;
  const int tile = ((bid & 7) << 5) | (bid >> 3);   // XCD-chunked
  const int brow = (tile >> 4) << 6, bcol = (tile & 15) << 6;
  const int kb = split << 8;
  const int lane = tid & 63, w = tid >> 6;
  const int wr = w >> 1, wc = w & 1;
  const int fr = lane & 15, kg = lane >> 4;
  const int srow = tid >> 2, sc0 = (tid & 3) * 8;

  const unsigned short* ap = A + (long)(brow + srow) * 1024 + kb + sc0;
  const unsigned short* bp = BT + (long)(bcol + srow) * 1024 + kb + sc0;

  f32x4 acc[2][2] = {{{0.f, 0.f, 0.f, 0.f}, {0.f, 0.f, 0.f, 0.f}},
                     {{0.f, 0.f, 0.f, 0.f}, {0.f, 0.f, 0.f, 0.f}}};

  ushort8 sa = *reinterpret_cast<const ushort8*>(ap);
  ushort8 sb = *reinterpret_cast<const ushort8*>(bp);
  int buf = 0;
  for (int kt = 0; kt < 256; kt += 32) {
    *reinterpret_cast<ushort8*>(&As[buf][srow][sc0]) = sa;
    *reinterpret_cast<ushort8*>(&Bs[buf][srow][sc0]) = sb;
    __syncthreads();
    if (kt + 32 < 256) {
      sa = *reinterpret_cast<const ushort8*>(ap + kt + 32);
      sb = *reinterpret_cast<const ushort8*>(bp + kt + 32);
    }
#ifdef HAVE_MFMA32
    short8 a0 = *reinterpret_cast<const short8*>(&As[buf][wr * 32 + fr][kg * 8]);
    short8 a1 = *reinterpret_cast<const short8*>(&As[buf][wr * 32 + 16 + fr][kg * 8]);
    short8 b0 = *reinterpret_cast<const short8*>(&Bs[buf][wc * 32 + fr][kg * 8]);
    short8 b1 = *reinterpret_cast<const short8*>(&Bs[buf][wc * 32 + 16 + fr][kg * 8]);
    acc[0][0] = mfma32(a0, b0, acc[0][0]);
    acc[0][1] = mfma32(a0, b1, acc[0][1]);
    acc[1][0] = mfma32(a1, b0, acc[1][0]);
    acc[1][1] = mfma32(a1, b1, acc[1][1]);
#else
#pragma unroll
    for (int kq = 0; kq < 2; ++kq) {
#pragma unroll
      for (int m = 0; m < 2; ++m) {
        bf16x4 a = *reinterpret_cast<const bf16x4*>(&As[buf][wr * 32 + m * 16 + fr][kq * 16 + kg * 4]);
#pragma unroll
        for (int n = 0; n < 2; ++n) {
          bf16x4 b = *reinterpret_cast<const bf16x4*>(&Bs[buf][wc * 32 + n * 16 + fr][kq * 16 + kg * 4]);
          acc[m][n] = mfma16(a, b, acc[m][n]);
        }
      }
    }
#endif
    buf ^= 1;
  }

  float* dst = P + (long)split * 1024 * 1024;
  if (MODE == 0) {
#pragma unroll
    for (int n = 0; n < 2; ++n) {
      const int colc = bcol + wc * 32 + n * 16 + fr;
#pragma unroll
      for (int m = 0; m < 2; ++m)
#pragma unroll
        for (int j = 0; j < 4; ++j) {
          int row = brow + wr * 32 + m * 16 + kg * 4 + j;
          dst[(long)row * 1024 + colc] = acc[m][n][j];
        }
    }
  } else {
#pragma unroll
    for (int n = 0; n < 2; ++n) {
      const int colc = bcol + wc * 32 + n * 16 + fr;
      const float bv = (split == 0) ? bias[colc] : 0.f;
      const int h = colc & 7, qqi = (colc >> 3) & 15, chi = colc >> 7;
#pragma unroll
      for (int m = 0; m < 2; ++m)
#pragma unroll
        for (int j = 0; j < 4; ++j) {
          int row = brow + wr * 32 + m * 16 + kg * 4 + j;
          int b = row >> 9, s = row & 511, g = s >> 7;
          int sd = (s & 127) * 8 + chi;
          int bgh = b * 32 + g * 8 + h;
          dst[((long)bgh * 1024 + sd) * 16 + qqi] = acc[m][n][j] + bv;
        }
    }
  }
}

// ---------------------------------------------------------------------------
// MFMA flash attention. Q fragment = sum of the 4 split-K f32 partials
// (bias already folded into split 0) -> bf16. Swapped-operand scheme:
//   S^T[n][sd] = mfma(A=K[n][q], B=Q^T[q][sd]); online softmax (column-local);
//   O^T[v][sd] = mfma(A=V^T[v][n], B=P^T[n][sd])  — S^T C-layout == P^T B-layout.
// conn_sub (134 MB, the dominant stream) read as float4 straight to registers.
// ---------------------------------------------------------------------------
__global__ __launch_bounds__(256) void attn_mfma(
    const float* __restrict__ qp, const unsigned short* __restrict__ KTb,
    const unsigned short* __restrict__ VTb, const float* __restrict__ conn,
    float* __restrict__ ln_in) {
  __shared__ float O_lds[4][16][17];

  const int tid = threadIdx.x;
  const int wid = tid >> 6, lane = tid & 63;
  const int c = lane & 15, hi = lane >> 4;
  const int rb = blockIdx.x;
  const int bgh = blockIdx.y;
  const int b = bgh >> 5, g = (bgh >> 3) & 3, h = bgh & 7;
  const int sd = rb * 64 + wid * 16 + c;

  const float* q0 = qp + ((long)bgh * 1024 + sd) * 16 + hi * 4;
  f32x4 qs = *reinterpret_cast<const f32x4*>(q0);
  qs += *reinterpret_cast<const f32x4*>(q0 + 1048576);
  qs += *reinterpret_cast<const f32x4*>(q0 + 2097152);
  qs += *reinterpret_cast<const f32x4*>(q0 + 3145728);
  bf16x4 qb;
  qb[0] = (short)f2bf(qs[0]);
  qb[1] = (short)f2bf(qs[1]);
  qb[2] = (short)f2bf(qs[2]);
  qb[3] = (short)f2bf(qs[3]);

  const unsigned short* kp = KTb + (long)bgh * 8192 + hi * 4;
  const unsigned short* vp = VTb + (long)bgh * 8192 + (long)c * 512 + hi * 4;
  const float* cp = conn + ((long)bgh * 1024 + sd) * 512 + hi * 4;

  f32x4 acc = {0.f, 0.f, 0.f, 0.f};
  float m = -1e30f, lsum = 0.f;

  for (int nb = 0; nb < 512; nb += 64) {
    f32x4 sv[4];
    float cv[16];
    const f32x4 zero = {0.f, 0.f, 0.f, 0.f};
#pragma unroll
    for (int t = 0; t < 4; ++t) {
      const int n0 = nb + t * 16;
      bf16x4 ka = *reinterpret_cast<const bf16x4*>(kp + (long)(n0 + c) * 16);
      float4 cf = *reinterpret_cast<const float4*>(cp + n0);
      sv[t] = mfma16(ka, qb, zero);
      cv[t * 4 + 0] = cf.x;
      cv[t * 4 + 1] = cf.y;
      cv[t * 4 + 2] = cf.z;
      cv[t * 4 + 3] = cf.w;
    }
    float s[16];
#pragma unroll
    for (int t = 0; t < 4; ++t)
#pragma unroll
      for (int r = 0; r < 4; ++r) s[t * 4 + r] = sv[t][r] * 0.25f - cv[t * 4 + r];

    float cmax = s[0];
#pragma unroll
    for (int j = 1; j < 16; ++j) cmax = fmaxf(cmax, s[j]);
    cmax = fmaxf(cmax, __shfl_xor(cmax, 16, 64));
    cmax = fmaxf(cmax, __shfl_xor(cmax, 32, 64));
    const float mnew = fmaxf(m, cmax);
    const float fac = __expf(m - mnew);
    acc *= fac;
    lsum *= fac;
    float p[16];
    float csum = 0.f;
#pragma unroll
    for (int j = 0; j < 16; ++j) {
      p[j] = __expf(s[j] - mnew);
      csum += p[j];
    }
    lsum += csum;
    m = mnew;
#pragma unroll
    for (int t = 0; t < 4; ++t) {
      const int n0 = nb + t * 16;
      bf16x4 pb;
      pb[0] = (short)f2bf(p[t * 4 + 0]);
      pb[1] = (short)f2bf(p[t * 4 + 1]);
      pb[2] = (short)f2bf(p[t * 4 + 2]);
      pb[3] = (short)f2bf(p[t * 4 + 3]);
      bf16x4 va = *reinterpret_cast<const bf16x4*>(vp + n0);
      acc = mfma16(va, pb, acc);
    }
  }

  lsum += __shfl_xor(lsum, 16, 64);
  lsum += __shfl_xor(lsum, 32, 64);
  const float rinv = 1.0f / lsum;
#pragma unroll
  for (int r = 0; r < 4; ++r) O_lds[wid][c][hi * 4 + r] = acc[r] * rinv;
  __syncthreads();

  const int dd = (rb * 64) >> 9;
  const int chb = g * 256 + h * 32 + dd * 16;
#pragma unroll
  for (int pass = 0; pass < 4; ++pass) {
    int rr = pass * 16 + (tid >> 4);
    int v = tid & 15;
    int ssi = (rb * 64 + rr) & 511;
    ln_in[(long)(b * 512 + ssi) * 1024 + chb + v] = O_lds[rr >> 4][rr & 15][v];
  }
}

// ---------------------------------------------------------------------------
// LayerNorm over last dim (1024); reads f32, writes bf16 (A of final GEMM).
// ---------------------------------------------------------------------------
__global__ __launch_bounds__(256) void ln_kernel(
    const float* __restrict__ x, const float* __restrict__ gamma,
    const float* __restrict__ beta, unsigned short* __restrict__ out) {
  const int row = blockIdx.x;
  const int tid = threadIdx.x;
  float4 v = *reinterpret_cast<const float4*>(&x[(long)row * 1024 + tid * 4]);
  float s = v.x + v.y + v.z + v.w;
  float s2 = v.x * v.x + v.y * v.y + v.z * v.z + v.w * v.w;
#pragma unroll
  for (int w = 32; w >= 1; w >>= 1) {
    s += __shfl_xor(s, w, 64);
    s2 += __shfl_xor(s2, w, 64);
  }
  __shared__ float red[8];
  const int lane = tid & 63, wid = tid >> 6;
  if (lane == 0) {
    red[wid] = s;
    red[wid + 4] = s2;
  }
  __syncthreads();
  s = red[0] + red[1] + red[2] + red[3];
  s2 = red[4] + red[5] + red[6] + red[7];
  const float mu = s * (1.0f / 1024.0f);
  const float var = s2 * (1.0f / 1024.0f) - mu * mu;
  const float rstd = rsqrtf(var + 1e-5f);
  float4 g4 = *reinterpret_cast<const float4*>(&gamma[tid * 4]);
  float4 b4 = *reinterpret_cast<const float4*>(&beta[tid * 4]);
  unsigned short o[4];
  o[0] = f2bf((v.x - mu) * rstd * g4.x + b4.x);
  o[1] = f2bf((v.y - mu) * rstd * g4.y + b4.y);
  o[2] = f2bf((v.z - mu) * rstd * g4.z + b4.z);
  o[3] = f2bf((v.w - mu) * rstd * g4.w + b4.w);
  *reinterpret_cast<uint2*>(&out[(long)row * 1024 + tid * 4]) = *reinterpret_cast<uint2*>(o);
}

// ---------------------------------------------------------------------------
// Final reduction: out[row][col] = sum_{s<4} wp[s][row][col] + bre[col].
// 512 blocks x 256 threads x 8 floats.
// ---------------------------------------------------------------------------
__global__ __launch_bounds__(256) void reduce_bias(
    const float* __restrict__ P, const float* __restrict__ bre,
    float* __restrict__ out) {
  const long i = ((long)blockIdx.x * 256 + threadIdx.x) * 8;
  f32x4 r0 = *reinterpret_cast<const f32x4*>(&P[i]);
  f32x4 r1 = *reinterpret_cast<const f32x4*>(&P[i + 4]);
  r0 += *reinterpret_cast<const f32x4*>(&P[1048576 + i]);
  r1 += *reinterpret_cast<const f32x4*>(&P[1048576 + i + 4]);
  r0 += *reinterpret_cast<const f32x4*>(&P[2097152 + i]);
  r1 += *reinterpret_cast<const f32x4*>(&P[2097152 + i + 4]);
  r0 += *reinterpret_cast<const f32x4*>(&P[3145728 + i]);
  r1 += *reinterpret_cast<const f32x4*>(&P[3145728 + i + 4]);
  const int col = (int)(i & 1023);
  r0 += *reinterpret_cast<const f32x4*>(&bre[col]);
  r1 += *reinterpret_cast<const f32x4*>(&bre[col + 4]);
  *reinterpret_cast<f32x4*>(&out[i]) = r0;
  *reinterpret_cast<f32x4*>(&out[i + 4]) = r1;
}

// ---------------------------------------------------------------------------
extern "C" void kernel_launch(void* const* d_in, const int* in_sizes, int n_in,
                              void* d_out, int out_size, void* d_ws,
                              size_t ws_size, hipStream_t stream) {
  const float* emb = (const float*)d_in[0];
  const float* keys = (const float*)d_in[1];
  const float* values = (const float*)d_in[2];
  const float* conn = (const float*)d_in[3];
  const float* Wq = (const float*)d_in[4];
  const float* bq = (const float*)d_in[5];
  const float* ln_g = (const float*)d_in[6];
  const float* ln_b = (const float*)d_in[7];
  const float* Wre = (const float*)d_in[8];
  const float* bre = (const float*)d_in[9];
  float* out = (float*)d_out;

  // workspace (28 MB; d_ws is ~512 MiB per the fill-kernel WRITE_SIZE):
  char* w = (char*)d_ws;
  float* ws_qp = (float*)w;                 // 16 MB: qp[4][1M] f32; aliased as wp for gemm2
  float* ws_wp = ws_qp;                     //   (disjoint lifetimes: qp stages 2-3, wp 5-6)
  float* ws_ln = (float*)(w + 16 * 1024 * 1024);                     // 4 MB
  unsigned short* ws_Ab = (unsigned short*)(w + 20 * 1024 * 1024);   // 2 MB
  unsigned short* ws_WqT = (unsigned short*)(w + 22 * 1024 * 1024);  // 2 MB
  unsigned short* ws_WreT = (unsigned short*)(w + 24 * 1024 * 1024); // 2 MB
  unsigned short* ws_KTb = (unsigned short*)(w + 26 * 1024 * 1024);  // 1 MB
  unsigned short* ws_VTb = (unsigned short*)(w + 27 * 1024 * 1024);  // 1 MB

  prep_all<<<1088, 256, 0, stream>>>(Wq, Wre, keys, values, emb,
                                     ws_WqT, ws_WreT, ws_KTb, ws_VTb, ws_Ab);
  gemm_splitk<1><<<dim3(256, 4), 256, 0, stream>>>(ws_Ab, ws_WqT, bq, ws_qp);
  attn_mfma<<<dim3(16, 64), 256, 0, stream>>>(ws_qp, ws_KTb, ws_VTb, conn, ws_ln);
  ln_kernel<<<1024, 256, 0, stream>>>(ws_ln, ln_g, ln_b, ws_Ab);
  gemm_splitk<0><<<dim3(256, 4), 256, 0, stream>>>(ws_Ab, ws_WreT, bre, ws_wp);
  reduce_bias<<<512, 256, 0, stream>>>(ws_wp, bre, out);
}